// Round 3
// baseline (80227.393 us; speedup 1.0000x reference)
//
#include <hip/hip_runtime.h>
#include <stdint.h>

// ---------------------------------------------------------------------------
// StabilizedNeuralODE v4: continuous global_load_lds weight stream,
// race-free slot ring.
//
// v3 had a ring-slot overwrite race (group g+5 issued before group g's data
// was read). v4 per-iteration order:
//     s_waitcnt vmcnt(4)            ; consumed groups complete
//     ds_read slot fragments -> VGPRs
//     s_waitcnt lgkmcnt(0)          ; data safely in registers
//     issue next 2 groups (glds)    ; may overwrite retired slots only
//     MFMAs
// Issue-to-consume distance is 2 iterations (>= L2 hit latency). The weight
// stream is identical every stage and crosses phase/stage barriers (raw
// s_barrier + lgkmcnt(0) only -- vmcnt is never drained in the loop).
//
// Structure: 32 WGs x 512 threads (8 waves, 2/SIMD); WG owns 16 batch rows
// for the whole trajectory. Weights pre-packed to bf16 in d_ws; per stage
// each wave streams 50 groups x 2 KB through a private 5-slot LDS ring
// (50 % 5 == 0 -> static slot schedule). Per-lane glds source addresses
// gather weights directly into MFMA B-fragment order; fragment ds_reads are
// lane*16 (conflict-free). Activations (y/h1/h2) in fragment order in LDS;
// k1..k6 and the RK combine live entirely in registers.
//
// MFMA 16x16x32_bf16 (verified): A-frag A[m=l16][k=quad*8+j],
// B-frag B[n=l16][k=quad*8+j], C/D n=l16, m=quad*4+reg.
// ---------------------------------------------------------------------------

#define Dd 128
#define Ww 512
#define Tt 512
#define NSTEP 511
#define NWG 32
#define NTHR 512

// workspace (ushort element offsets): bf16 row-major weights
#define WS_W1 0         // 512 x 128
#define WS_W2 65536     // 512 x 512
#define WS_W3 327680    // 128 x 512
#define WS_A  393216    // 128 x 128
#define WS_TOT 409600   // 819,200 bytes

// LDS byte offsets
#define RING_PER_WAVE 10240   // 5 slots x 2048 B
#define H1F 81920             // 16 x 512 bf16, fragment order (16 KB)
#define H2F 98304
#define Y0F 114688            // 16 x 128 bf16 frags (4 KB)
#define Y1F 118784
#define ATF 122880            // 6 x 8 f32 RK rows (192 B)
#define DTF 123072            // 511 f32 dt values
#define SMEMB 125120

typedef __attribute__((ext_vector_type(8))) __bf16 bf16x8;
typedef __attribute__((ext_vector_type(4))) float f32x4;

__device__ __forceinline__ unsigned short f2b(float f) {
  union { float f; unsigned int u; } v; v.f = f;
  return (unsigned short)((v.u + 0x7fffu + ((v.u >> 16) & 1u)) >> 16);
}
__device__ __forceinline__ float fast_tanh(float x) {
  x = fminf(fmaxf(x, -15.f), 15.f);
  float e = __expf(2.f * x);
  return (e - 1.f) / (e + 1.f);
}
// frag byte address of element (m=batch row 0..15, n=feature col):
// tile n>>5 (1 KB), lane ((n>>3)&3)*16+m (16 B), elem n&7.
__device__ __forceinline__ int fragaddr(int m, int n) {
  return ((n >> 5) << 10) + ((((n >> 3) & 3) * 16 + m) << 4) + ((n & 7) << 1);
}

// RK coefficients: rows 0..4 = A(s+1,*) zero-padded to 8, row 5 = B.
__device__ const float RKC[48] = {
  0.161f, 0.f, 0.f, 0.f, 0.f, 0.f, 0.f, 0.f,
  -0.008480655492356989f, 0.335480655492357f, 0.f, 0.f, 0.f, 0.f, 0.f, 0.f,
  2.8971530571054935f, -6.359448489975075f, 4.3622954328695815f, 0.f, 0.f, 0.f, 0.f, 0.f,
  5.325864828439257f, -11.748883564062828f, 7.4955393428898365f,
  -0.09249506636175525f, 0.f, 0.f, 0.f, 0.f,
  5.86145544294642f, -12.92096931784711f, 8.159367898576159f,
  -0.071584973281401f, -0.028269050394068383f, 0.f, 0.f, 0.f,
  0.09646076681806523f, 0.01f, 0.4798896504144996f, 1.379008574103742f,
  -3.290069515436081f, 2.324710524099774f, 0.f, 0.f
};

#define GLDS(gp, lp) __builtin_amdgcn_global_load_lds( \
    (const __attribute__((address_space(1))) unsigned int*)(const void*)(gp), \
    (__attribute__((address_space(3))) unsigned int*)(void*)(lp), 16, 0, 0)

#define SLOTP(g) (ring_w + (((g) % 5) * 2048))

// counted wait BEFORE slot reads: completes the 2 groups consumed this iter,
// leaves 2 groups (4 glds) in flight. Never vmcnt(0) in the loop.
#define VMW4() do { asm volatile("s_waitcnt vmcnt(4)" ::: "memory"); \
                    __builtin_amdgcn_sched_barrier(0); } while (0)
// slot data provably in VGPRs before any overwrite can be issued
#define LGKM0() do { asm volatile("s_waitcnt lgkmcnt(0)" ::: "memory"); \
                     __builtin_amdgcn_sched_barrier(0); } while (0)
// barrier that does NOT drain vmcnt
#define LBAR() do { asm volatile("s_waitcnt lgkmcnt(0)" ::: "memory"); \
                    __builtin_amdgcn_s_barrier(); } while (0)

// issue group g (2 x 1KB fragment tiles -> slot g%5). Group ids:
// 0..7 w1 (nt pair g&1, ks g>>1); 8..39 w2; 40..47 w3 (ks pair g-40);
// 48..49 A (ks pair g-48).
#define ISSUE_W1(g) do { GLDS(gw1[((g)&1)*2]   + ((g)>>1)*32, SLOTP(g)); \
                         GLDS(gw1[((g)&1)*2+1] + ((g)>>1)*32, SLOTP(g)+1024); } while (0)
#define ISSUE_W2(g) do { GLDS(gw2[(((g)-8)&1)*2]   + (((g)-8)>>1)*32, SLOTP(g)); \
                         GLDS(gw2[(((g)-8)&1)*2+1] + (((g)-8)>>1)*32, SLOTP(g)+1024); } while (0)
#define ISSUE_W3(g) do { GLDS(gw3 + (2*((g)-40))*32,   SLOTP(g)); \
                         GLDS(gw3 + (2*((g)-40)+1)*32, SLOTP(g)+1024); } while (0)
#define ISSUE_A(g)  do { GLDS(gA + (2*((g)-48))*32,   SLOTP(g)); \
                         GLDS(gA + (2*((g)-48)+1)*32, SLOTP(g)+1024); } while (0)

#define MFMA(a, b, c) __builtin_amdgcn_mfma_f32_16x16x32_bf16((a), (b), (c), 0, 0, 0)
#define CPK(kd) do { kd[0]=kk[0]; kd[1]=kk[1]; kd[2]=kk[2]; kd[3]=kk[3]; } while (0)

// one-time fp32 -> bf16 pack (row-major) of w1,w2,w3,A into workspace
__global__ void prep_kernel(const float* __restrict__ w1,
                            const float* __restrict__ w2,
                            const float* __restrict__ w3,
                            const float* __restrict__ Am,
                            unsigned short* __restrict__ wsb) {
  for (int i = blockIdx.x * blockDim.x + threadIdx.x; i < WS_TOT;
       i += gridDim.x * blockDim.x) {
    float v;
    if (i < WS_W2)      v = w1[i];
    else if (i < WS_W3) v = w2[i - WS_W2];
    else if (i < WS_A)  v = w3[i - WS_W3];
    else                v = Am[i - WS_A];
    wsb[i] = f2b(v);
  }
}

__global__ void __launch_bounds__(NTHR, 1)
ode_kernel(const float* __restrict__ ts,
           const float* __restrict__ yi,
           const float* __restrict__ b1,
           const float* __restrict__ b2,
           const float* __restrict__ b3,
           float* __restrict__ out,
           const unsigned short* __restrict__ wsb)
{
  extern __shared__ char smem_c[];

  const int tid  = threadIdx.x;
  const int wid  = tid >> 6;
  const int lane = tid & 63;
  const int l16  = lane & 15;
  const int quad = lane >> 4;
  const int lob  = lane << 4;          // lane*16 bytes
  const int b0   = blockIdx.x * 16;

  char* ring_w = smem_c + wid * RING_PER_WAVE;
  char* h1f = smem_c + H1F;
  char* h2f = smem_c + H2F;

  // ---- per-lane global fragment-gather base pointers ----
  // lane L = quad*16+l16 fetches weight row (n0+l16), k cols quad*8..+8;
  // lands at slot+L*16 == the B-fragment ds_read_b128 address.
  const unsigned short* gw1[4];
  const unsigned short* gw2[4];
  #pragma unroll
  for (int nt = 0; nt < 4; ++nt) {
    int row = (wid << 6) + (nt << 4) + l16;
    gw1[nt] = wsb + WS_W1 + row * Dd + quad * 8;
    gw2[nt] = wsb + WS_W2 + row * Ww + quad * 8;
  }
  const unsigned short* gw3 = wsb + WS_W3 + ((wid << 4) + l16) * Ww + quad * 8;
  const unsigned short* gA  = wsb + WS_A  + ((wid << 4) + l16) * Dd + quad * 8;

  // ---- one-time staging: RK table + dt into LDS; biases into regs ----
  if (tid < 48) *(float*)(smem_c + ATF + (tid << 2)) = RKC[tid];
  for (int i = tid; i < NSTEP; i += NTHR)
    *(float*)(smem_c + DTF + (i << 2)) = ts[i + 1] - ts[i];

  float b1v[4], b2v[4];
  #pragma unroll
  for (int nt = 0; nt < 4; ++nt) {
    b1v[nt] = b1[(wid << 6) + (nt << 4) + l16];
    b2v[nt] = b2[(wid << 6) + (nt << 4) + l16];
  }
  const float b3v = b3[(wid << 4) + l16];

  // h-frag write bases: n = wid*64+nt*16+l16, m = quad*4 (+r lanes = r*16 B)
  int hwaddr[4];
  #pragma unroll
  for (int nt = 0; nt < 4; ++nt)
    hwaddr[nt] = fragaddr(quad << 2, (wid << 6) + (nt << 4) + l16);
  const int nC = (wid << 4) + l16;          // phase C/D column
  const int ydst = fragaddr(quad << 2, nC); // y-frag write base

  // ---- y0: 4 fp32 regs (rows quad*4+r, col nC), Y0F frags, out[t=0] ----
  float y[4];
  #pragma unroll
  for (int r = 0; r < 4; ++r) {
    y[r] = yi[(size_t)(b0 + (quad << 2) + r) * Dd + nC];
    *(unsigned short*)(smem_c + Y0F + ydst + (r << 4)) = f2b(y[r]);
    out[(size_t)(b0 + (quad << 2) + r) * (Tt * Dd) + nC] = y[r];
  }

  float k0[4] = {0,0,0,0}, k1[4] = {0,0,0,0}, k2[4] = {0,0,0,0},
        k3[4] = {0,0,0,0}, k4[4] = {0,0,0,0}, k5[4] = {0,0,0,0};

  // drains all init vmem (compiler then emits no stray waits on b1v/y/etc.)
  __syncthreads();

  // pipeline prologue: groups 0..3 in flight (slots 0..3)
  ISSUE_W1(0); ISSUE_W1(1); ISSUE_W1(2); ISSUE_W1(3);

  #pragma unroll 1
  for (int t = 0; t < NSTEP; ++t) {
    const float hdt = *(const float*)(smem_c + DTF + (t << 2));

    #pragma unroll 1
    for (int s = 0; s < 6; ++s) {
      const char* ybr = smem_c + ((s & 1) ? Y1F : Y0F);
      char*       ybw = smem_c + ((s & 1) ? Y0F : Y1F);

      LBAR();   // y(parity) ready; h buffers free

      // ---- phase A: h1 = tanh(a @ w1.T + b1); consume groups 0..7 -------
      {
        f32x4 accA[4];
        #pragma unroll
        for (int nt = 0; nt < 4; ++nt) { f32x4 z = {0.f,0.f,0.f,0.f}; accA[nt] = z; }
        #pragma unroll
        for (int ks = 0; ks < 4; ++ks) {
          VMW4();
          bf16x8 af = *(const bf16x8*)(ybr + (ks << 10) + lob);
          bf16x8 bv[4];
          #pragma unroll
          for (int nt = 0; nt < 4; ++nt)
            bv[nt] = *(const bf16x8*)(SLOTP(2*ks + (nt >> 1)) +
                                      ((nt & 1) << 10) + lob);
          LGKM0();
          if (ks == 0)      { ISSUE_W1(4);  ISSUE_W1(5);  }
          else if (ks == 1) { ISSUE_W1(6);  ISSUE_W1(7);  }
          else if (ks == 2) { ISSUE_W2(8);  ISSUE_W2(9);  }
          else              { ISSUE_W2(10); ISSUE_W2(11); }
          #pragma unroll
          for (int nt = 0; nt < 4; ++nt)
            accA[nt] = MFMA(af, bv[nt], accA[nt]);
        }
        #pragma unroll
        for (int nt = 0; nt < 4; ++nt)
          #pragma unroll
          for (int r = 0; r < 4; ++r)
            *(unsigned short*)(h1f + hwaddr[nt] + (r << 4)) =
                f2b(fast_tanh(accA[nt][r] + b1v[nt]));
      }
      LBAR();   // h1 ready

      // ---- phase B: h2 = tanh(h1 @ w2.T + b2); consume groups 8..39 -----
      {
        f32x4 accB[4];
        #pragma unroll
        for (int nt = 0; nt < 4; ++nt) { f32x4 z = {0.f,0.f,0.f,0.f}; accB[nt] = z; }
        #pragma unroll
        for (int ks = 0; ks < 16; ++ks) {
          VMW4();
          bf16x8 af = *(const bf16x8*)(h1f + (ks << 10) + lob);
          bf16x8 bv[4];
          #pragma unroll
          for (int nt = 0; nt < 4; ++nt)
            bv[nt] = *(const bf16x8*)(SLOTP(8 + 2*ks + (nt >> 1)) +
                                      ((nt & 1) << 10) + lob);
          LGKM0();
          if (ks < 14)       { ISSUE_W2(12 + 2*ks); ISSUE_W2(13 + 2*ks); }
          else if (ks == 14) { ISSUE_W3(40); ISSUE_W3(41); }
          else               { ISSUE_W3(42); ISSUE_W3(43); }
          #pragma unroll
          for (int nt = 0; nt < 4; ++nt)
            accB[nt] = MFMA(af, bv[nt], accB[nt]);
        }
        #pragma unroll
        for (int nt = 0; nt < 4; ++nt)
          #pragma unroll
          for (int r = 0; r < 4; ++r)
            *(unsigned short*)(h2f + hwaddr[nt] + (r << 4)) =
                f2b(fast_tanh(accB[nt][r] + b2v[nt]));
      }
      LBAR();   // h2 ready

      // ---- phase C: k = h2 @ w3.T + b3 + a @ A.T; consume groups 40..49 -
      {
        f32x4 accC0 = {0.f, 0.f, 0.f, 0.f};
        f32x4 accC1 = {0.f, 0.f, 0.f, 0.f};
        #pragma unroll
        for (int cc = 0; cc < 5; ++cc) {
          VMW4();
          bf16x8 afv[4], bv[4];
          #pragma unroll
          for (int t4 = 0; t4 < 4; ++t4) {
            const char* ab = (cc < 4) ? (h2f + ((4*cc + t4) << 10))
                                      : (ybr + (t4 << 10));
            afv[t4] = *(const bf16x8*)(ab + lob);
            bv[t4]  = *(const bf16x8*)(SLOTP(40 + 2*cc + (t4 >> 1)) +
                                       ((t4 & 1) << 10) + lob);
          }
          LGKM0();
          if (cc == 0)      { ISSUE_W3(44); ISSUE_W3(45); }
          else if (cc == 1) { ISSUE_W3(46); ISSUE_W3(47); }
          else if (cc == 2) { ISSUE_A(48);  ISSUE_A(49);  }
          else if (cc == 3) { ISSUE_W1(0);  ISSUE_W1(1);  }  // next stage
          else              { ISSUE_W1(2);  ISSUE_W1(3);  }
          accC0 = MFMA(afv[0], bv[0], accC0);
          accC1 = MFMA(afv[1], bv[1], accC1);
          accC0 = MFMA(afv[2], bv[2], accC0);
          accC1 = MFMA(afv[3], bv[3], accC1);
        }
        float kk[4];
        #pragma unroll
        for (int r = 0; r < 4; ++r) kk[r] = accC0[r] + accC1[r] + b3v;
        switch (s) {
          case 0: CPK(k0); break;
          case 1: CPK(k1); break;
          case 2: CPK(k2); break;
          case 3: CPK(k3); break;
          case 4: CPK(k4); break;
          default: CPK(k5); break;
        }
      }

      // ---- phase D: RK combine in registers; write y-stage frags --------
      {
        const float* cp = (const float*)(smem_c + ATF + (s << 5));
        const float c0 = cp[0], c1 = cp[1], c2 = cp[2];
        const float c3 = cp[3], c4 = cp[4], c5 = cp[5];
        float a_[4];
        #pragma unroll
        for (int r = 0; r < 4; ++r)
          a_[r] = y[r] + hdt * (c0*k0[r] + c1*k1[r] + c2*k2[r] +
                                c3*k3[r] + c4*k4[r] + c5*k5[r]);
        #pragma unroll
        for (int r = 0; r < 4; ++r)
          *(unsigned short*)(ybw + ydst + (r << 4)) = f2b(a_[r]);
        if (s == 5) {
          #pragma unroll
          for (int r = 0; r < 4; ++r) {
            y[r] = a_[r];
            out[(size_t)(b0 + (quad << 2) + r) * (Tt * Dd) +
                (size_t)(t + 1) * Dd + nC] = a_[r];
          }
        }
      }
    } // stages
  } // steps
}

extern "C" void kernel_launch(void* const* d_in, const int* in_sizes, int n_in,
                              void* d_out, int out_size, void* d_ws, size_t ws_size,
                              hipStream_t stream) {
  (void)in_sizes; (void)n_in; (void)out_size; (void)ws_size;

  const float* ts = (const float*)d_in[0];
  const float* yi = (const float*)d_in[1];
  const float* w1 = (const float*)d_in[2];
  const float* b1 = (const float*)d_in[3];
  const float* w2 = (const float*)d_in[4];
  const float* b2 = (const float*)d_in[5];
  const float* w3 = (const float*)d_in[6];
  const float* b3 = (const float*)d_in[7];
  const float* Am = (const float*)d_in[8];
  float* outp = (float*)d_out;
  unsigned short* wsb = (unsigned short*)d_ws;

  (void)hipFuncSetAttribute(reinterpret_cast<const void*>(ode_kernel),
                            hipFuncAttributeMaxDynamicSharedMemorySize,
                            SMEMB);

  prep_kernel<<<400, 256, 0, stream>>>(w1, w2, w3, Am, wsb);
  ode_kernel<<<dim3(NWG), dim3(NTHR), SMEMB, stream>>>(
      ts, yi, b1, b2, b3, outp, wsb);
}

// Round 4
// 37055.481 us; speedup vs baseline: 2.1651x; 2.1651x over previous
//
#include <hip/hip_runtime.h>
#include <stdint.h>

// ---------------------------------------------------------------------------
// StabilizedNeuralODE v5: coalesced pre-permuted weight stream.
//
// v4 (80 ms, PASSED) proved the glds ring + counted-vmcnt pipeline correct,
// but its per-lane gather addresses (stride 256B-1KB across lanes) shattered
// every glds into ~64 cache-line transactions: 51,200 line-transactions per
// stage per CU ~= 21 us/stage. v5 moves the fragment-order permutation into
// prep_kernel: the workspace holds, per wave, the 50-group x 2KB stream in
// EXACT consumption order, so every glds is base + lane*16 -- fully
// coalesced (8 x 128B lines per instruction, 8x fewer transactions).
// The ode kernel's consumption code, slot ring, vmcnt/barrier discipline are
// byte-identical to v4 (verified correct).
//
// Structure: 32 WGs x 512 threads (8 waves, 2/SIMD); WG owns 16 batch rows.
// Per stage each wave streams 50 groups x 2 KB through a private 5-slot LDS
// ring; issue runs 2 groups ahead of consume (distance 2 iterations >= L2
// latency), crossing phase AND stage barriers (raw s_barrier + lgkmcnt(0);
// vmcnt never drained in the loop).
//
// Stream order per wave w (group g -> contents):
//   g 0..7  : w1, nt=(g&1)*2+tile, ks=g>>1
//   g 8..39 : w2, gg=g-8, nt=(gg&1)*2+tile, ks=gg>>1
//   g 40..47: w3, kcol=2*(g-40)+tile
//   g 48..49: A,  kcol=2*(g-48)+tile
// Tile layout (1 KB): lane L=(q*16+l16) holds row (n0+l16), cols k0+q*8..+8
// == MFMA B-fragment order, ds_read_b128 at lane*16 (conflict-free).
//
// MFMA 16x16x32_bf16 (verified): A-frag A[m=l16][k=quad*8+j],
// B-frag B[n=l16][k=quad*8+j], C/D n=l16, m=quad*4+reg.
// ---------------------------------------------------------------------------

#define Dd 128
#define Ww 512
#define Tt 512
#define NSTEP 511
#define NWG 32
#define NTHR 512

// permuted stream: 8 waves x 50 groups x 1024 ushort = 409,600 ushort
#define GRP_USH 1024
#define WAVE_USH (50 * GRP_USH)
#define WS_TOT (8 * WAVE_USH)

// LDS byte offsets
#define RING_PER_WAVE 10240   // 5 slots x 2048 B
#define H1F 81920             // 16 x 512 bf16, fragment order (16 KB)
#define H2F 98304
#define Y0F 114688            // 16 x 128 bf16 frags (4 KB)
#define Y1F 118784
#define ATF 122880            // 6 x 8 f32 RK rows (192 B)
#define DTF 123072            // 511 f32 dt values
#define SMEMB 125120

typedef __attribute__((ext_vector_type(8))) __bf16 bf16x8;
typedef __attribute__((ext_vector_type(4))) float f32x4;

__device__ __forceinline__ unsigned short f2b(float f) {
  union { float f; unsigned int u; } v; v.f = f;
  return (unsigned short)((v.u + 0x7fffu + ((v.u >> 16) & 1u)) >> 16);
}
__device__ __forceinline__ float fast_tanh(float x) {
  x = fminf(fmaxf(x, -15.f), 15.f);
  float e = __expf(2.f * x);
  return (e - 1.f) / (e + 1.f);
}
// frag byte address of element (m=batch row 0..15, n=feature col):
// tile n>>5 (1 KB), lane ((n>>3)&3)*16+m (16 B), elem n&7.
__device__ __forceinline__ int fragaddr(int m, int n) {
  return ((n >> 5) << 10) + ((((n >> 3) & 3) * 16 + m) << 4) + ((n & 7) << 1);
}

// RK coefficients: rows 0..4 = A(s+1,*) zero-padded to 8, row 5 = B.
__device__ const float RKC[48] = {
  0.161f, 0.f, 0.f, 0.f, 0.f, 0.f, 0.f, 0.f,
  -0.008480655492356989f, 0.335480655492357f, 0.f, 0.f, 0.f, 0.f, 0.f, 0.f,
  2.8971530571054935f, -6.359448489975075f, 4.3622954328695815f, 0.f, 0.f, 0.f, 0.f, 0.f,
  5.325864828439257f, -11.748883564062828f, 7.4955393428898365f,
  -0.09249506636175525f, 0.f, 0.f, 0.f, 0.f,
  5.86145544294642f, -12.92096931784711f, 8.159367898576159f,
  -0.071584973281401f, -0.028269050394068383f, 0.f, 0.f, 0.f,
  0.09646076681806523f, 0.01f, 0.4798896504144996f, 1.379008574103742f,
  -3.290069515436081f, 2.324710524099774f, 0.f, 0.f
};

#define GLDS(gp, lp) __builtin_amdgcn_global_load_lds( \
    (const __attribute__((address_space(1))) unsigned int*)(const void*)(gp), \
    (__attribute__((address_space(3))) unsigned int*)(void*)(lp), 16, 0, 0)

#define SLOTP(g) (ring_w + (((g) % 5) * 2048))

// counted wait BEFORE slot reads: completes the 2 groups consumed this iter,
// leaves 2 groups (4 glds) in flight. Never vmcnt(0) in the loop.
#define VMW4() do { asm volatile("s_waitcnt vmcnt(4)" ::: "memory"); \
                    __builtin_amdgcn_sched_barrier(0); } while (0)
// slot data provably in VGPRs before any overwrite can be issued
#define LGKM0() do { asm volatile("s_waitcnt lgkmcnt(0)" ::: "memory"); \
                     __builtin_amdgcn_sched_barrier(0); } while (0)
// barrier that does NOT drain vmcnt
#define LBAR() do { asm volatile("s_waitcnt lgkmcnt(0)" ::: "memory"); \
                    __builtin_amdgcn_s_barrier(); } while (0)

// issue group g: 2 contiguous 1 KB tiles, lane-linear (fully coalesced)
#define ISSUE(g) do { \
    GLDS(gstream + ((g) << 10) + lsrc,       SLOTP(g)); \
    GLDS(gstream + ((g) << 10) + 512 + lsrc, SLOTP(g) + 1024); } while (0)

#define MFMA(a, b, c) __builtin_amdgcn_mfma_f32_16x16x32_bf16((a), (b), (c), 0, 0, 0)
#define CPK(kd) do { kd[0]=kk[0]; kd[1]=kk[1]; kd[2]=kk[2]; kd[3]=kk[3]; } while (0)

// one-time permute+convert: build the per-wave fragment-order bf16 stream
__global__ void prep_kernel(const float* __restrict__ w1,
                            const float* __restrict__ w2,
                            const float* __restrict__ w3,
                            const float* __restrict__ Am,
                            unsigned short* __restrict__ wsb) {
  for (int i = blockIdx.x * blockDim.x + threadIdx.x; i < WS_TOT;
       i += gridDim.x * blockDim.x) {
    const int j    = i & 7;
    const int L    = (i >> 3) & 63;
    const int l16  = L & 15;
    const int q    = L >> 4;
    const int tile = (i >> 9) & 1;
    const int g    = (i >> 10) % 50;
    const int w    = i / WAVE_USH;
    float v;
    if (g < 8) {
      const int nt = (g & 1) * 2 + tile, ks = g >> 1;
      v = w1[(w * 64 + nt * 16 + l16) * Dd + ks * 32 + q * 8 + j];
    } else if (g < 40) {
      const int gg = g - 8;
      const int nt = (gg & 1) * 2 + tile, ks = gg >> 1;
      v = w2[(w * 64 + nt * 16 + l16) * Ww + ks * 32 + q * 8 + j];
    } else if (g < 48) {
      const int kcol = 2 * (g - 40) + tile;
      v = w3[(w * 16 + l16) * Ww + kcol * 32 + q * 8 + j];
    } else {
      const int kcol = 2 * (g - 48) + tile;
      v = Am[(w * 16 + l16) * Dd + kcol * 32 + q * 8 + j];
    }
    wsb[i] = f2b(v);
  }
}

__global__ void __launch_bounds__(NTHR, 1)
ode_kernel(const float* __restrict__ ts,
           const float* __restrict__ yi,
           const float* __restrict__ b1,
           const float* __restrict__ b2,
           const float* __restrict__ b3,
           float* __restrict__ out,
           const unsigned short* __restrict__ wsb)
{
  extern __shared__ char smem_c[];

  const int tid  = threadIdx.x;
  const int wid  = tid >> 6;
  const int lane = tid & 63;
  const int l16  = lane & 15;
  const int quad = lane >> 4;
  const int lob  = lane << 4;          // lane*16 bytes (LDS frag reads)
  const int lsrc = lane << 3;          // lane*8 ushorts = 16 B (stream src)
  const int b0   = blockIdx.x * 16;

  char* ring_w = smem_c + wid * RING_PER_WAVE;
  char* h1f = smem_c + H1F;
  char* h2f = smem_c + H2F;

  // this wave's pre-permuted stream (consumption order)
  const unsigned short* gstream = wsb + wid * WAVE_USH;

  // ---- one-time staging: RK table + dt into LDS; biases into regs ----
  if (tid < 48) *(float*)(smem_c + ATF + (tid << 2)) = RKC[tid];
  for (int i = tid; i < NSTEP; i += NTHR)
    *(float*)(smem_c + DTF + (i << 2)) = ts[i + 1] - ts[i];

  float b1v[4], b2v[4];
  #pragma unroll
  for (int nt = 0; nt < 4; ++nt) {
    b1v[nt] = b1[(wid << 6) + (nt << 4) + l16];
    b2v[nt] = b2[(wid << 6) + (nt << 4) + l16];
  }
  const float b3v = b3[(wid << 4) + l16];

  // h-frag write bases: n = wid*64+nt*16+l16, m = quad*4 (+r lanes = r*16 B)
  int hwaddr[4];
  #pragma unroll
  for (int nt = 0; nt < 4; ++nt)
    hwaddr[nt] = fragaddr(quad << 2, (wid << 6) + (nt << 4) + l16);
  const int nC = (wid << 4) + l16;          // phase C/D column
  const int ydst = fragaddr(quad << 2, nC); // y-frag write base

  // ---- y0: 4 fp32 regs (rows quad*4+r, col nC), Y0F frags, out[t=0] ----
  float y[4];
  #pragma unroll
  for (int r = 0; r < 4; ++r) {
    y[r] = yi[(size_t)(b0 + (quad << 2) + r) * Dd + nC];
    *(unsigned short*)(smem_c + Y0F + ydst + (r << 4)) = f2b(y[r]);
    out[(size_t)(b0 + (quad << 2) + r) * (Tt * Dd) + nC] = y[r];
  }

  float k0[4] = {0,0,0,0}, k1[4] = {0,0,0,0}, k2[4] = {0,0,0,0},
        k3[4] = {0,0,0,0}, k4[4] = {0,0,0,0}, k5[4] = {0,0,0,0};

  // drains all init vmem
  __syncthreads();

  // pipeline prologue: groups 0..3 in flight (slots 0..3)
  ISSUE(0); ISSUE(1); ISSUE(2); ISSUE(3);

  #pragma unroll 1
  for (int t = 0; t < NSTEP; ++t) {
    const float hdt = *(const float*)(smem_c + DTF + (t << 2));

    #pragma unroll 1
    for (int s = 0; s < 6; ++s) {
      const char* ybr = smem_c + ((s & 1) ? Y1F : Y0F);
      char*       ybw = smem_c + ((s & 1) ? Y0F : Y1F);

      LBAR();   // y(parity) ready; h buffers free

      // ---- phase A: h1 = tanh(a @ w1.T + b1); consume groups 0..7 -------
      {
        f32x4 accA[4];
        #pragma unroll
        for (int nt = 0; nt < 4; ++nt) { f32x4 z = {0.f,0.f,0.f,0.f}; accA[nt] = z; }
        #pragma unroll
        for (int ks = 0; ks < 4; ++ks) {
          VMW4();
          bf16x8 af = *(const bf16x8*)(ybr + (ks << 10) + lob);
          bf16x8 bv[4];
          #pragma unroll
          for (int nt = 0; nt < 4; ++nt)
            bv[nt] = *(const bf16x8*)(SLOTP(2*ks + (nt >> 1)) +
                                      ((nt & 1) << 10) + lob);
          LGKM0();
          if (ks == 0)      { ISSUE(4);  ISSUE(5);  }
          else if (ks == 1) { ISSUE(6);  ISSUE(7);  }
          else if (ks == 2) { ISSUE(8);  ISSUE(9);  }
          else              { ISSUE(10); ISSUE(11); }
          #pragma unroll
          for (int nt = 0; nt < 4; ++nt)
            accA[nt] = MFMA(af, bv[nt], accA[nt]);
        }
        #pragma unroll
        for (int nt = 0; nt < 4; ++nt)
          #pragma unroll
          for (int r = 0; r < 4; ++r)
            *(unsigned short*)(h1f + hwaddr[nt] + (r << 4)) =
                f2b(fast_tanh(accA[nt][r] + b1v[nt]));
      }
      LBAR();   // h1 ready

      // ---- phase B: h2 = tanh(h1 @ w2.T + b2); consume groups 8..39 -----
      {
        f32x4 accB[4];
        #pragma unroll
        for (int nt = 0; nt < 4; ++nt) { f32x4 z = {0.f,0.f,0.f,0.f}; accB[nt] = z; }
        #pragma unroll
        for (int ks = 0; ks < 16; ++ks) {
          VMW4();
          bf16x8 af = *(const bf16x8*)(h1f + (ks << 10) + lob);
          bf16x8 bv[4];
          #pragma unroll
          for (int nt = 0; nt < 4; ++nt)
            bv[nt] = *(const bf16x8*)(SLOTP(8 + 2*ks + (nt >> 1)) +
                                      ((nt & 1) << 10) + lob);
          LGKM0();
          if (ks < 14)       { ISSUE(12 + 2*ks); ISSUE(13 + 2*ks); }
          else if (ks == 14) { ISSUE(40); ISSUE(41); }
          else               { ISSUE(42); ISSUE(43); }
          #pragma unroll
          for (int nt = 0; nt < 4; ++nt)
            accB[nt] = MFMA(af, bv[nt], accB[nt]);
        }
        #pragma unroll
        for (int nt = 0; nt < 4; ++nt)
          #pragma unroll
          for (int r = 0; r < 4; ++r)
            *(unsigned short*)(h2f + hwaddr[nt] + (r << 4)) =
                f2b(fast_tanh(accB[nt][r] + b2v[nt]));
      }
      LBAR();   // h2 ready

      // ---- phase C: k = h2 @ w3.T + b3 + a @ A.T; consume groups 40..49 -
      {
        f32x4 accC0 = {0.f, 0.f, 0.f, 0.f};
        f32x4 accC1 = {0.f, 0.f, 0.f, 0.f};
        #pragma unroll
        for (int cc = 0; cc < 5; ++cc) {
          VMW4();
          bf16x8 afv[4], bv[4];
          #pragma unroll
          for (int t4 = 0; t4 < 4; ++t4) {
            const char* ab = (cc < 4) ? (h2f + ((4*cc + t4) << 10))
                                      : (ybr + (t4 << 10));
            afv[t4] = *(const bf16x8*)(ab + lob);
            bv[t4]  = *(const bf16x8*)(SLOTP(40 + 2*cc + (t4 >> 1)) +
                                       ((t4 & 1) << 10) + lob);
          }
          LGKM0();
          if (cc == 0)      { ISSUE(44); ISSUE(45); }
          else if (cc == 1) { ISSUE(46); ISSUE(47); }
          else if (cc == 2) { ISSUE(48); ISSUE(49); }
          else if (cc == 3) { ISSUE(0);  ISSUE(1);  }  // next stage
          else              { ISSUE(2);  ISSUE(3);  }
          accC0 = MFMA(afv[0], bv[0], accC0);
          accC1 = MFMA(afv[1], bv[1], accC1);
          accC0 = MFMA(afv[2], bv[2], accC0);
          accC1 = MFMA(afv[3], bv[3], accC1);
        }
        float kk[4];
        #pragma unroll
        for (int r = 0; r < 4; ++r) kk[r] = accC0[r] + accC1[r] + b3v;
        switch (s) {
          case 0: CPK(k0); break;
          case 1: CPK(k1); break;
          case 2: CPK(k2); break;
          case 3: CPK(k3); break;
          case 4: CPK(k4); break;
          default: CPK(k5); break;
        }
      }

      // ---- phase D: RK combine in registers; write y-stage frags --------
      {
        const float* cp = (const float*)(smem_c + ATF + (s << 5));
        const float c0 = cp[0], c1 = cp[1], c2 = cp[2];
        const float c3 = cp[3], c4 = cp[4], c5 = cp[5];
        float a_[4];
        #pragma unroll
        for (int r = 0; r < 4; ++r)
          a_[r] = y[r] + hdt * (c0*k0[r] + c1*k1[r] + c2*k2[r] +
                                c3*k3[r] + c4*k4[r] + c5*k5[r]);
        #pragma unroll
        for (int r = 0; r < 4; ++r)
          *(unsigned short*)(ybw + ydst + (r << 4)) = f2b(a_[r]);
        if (s == 5) {
          #pragma unroll
          for (int r = 0; r < 4; ++r) {
            y[r] = a_[r];
            out[(size_t)(b0 + (quad << 2) + r) * (Tt * Dd) +
                (size_t)(t + 1) * Dd + nC] = a_[r];
          }
        }
      }
    } // stages
  } // steps
}

extern "C" void kernel_launch(void* const* d_in, const int* in_sizes, int n_in,
                              void* d_out, int out_size, void* d_ws, size_t ws_size,
                              hipStream_t stream) {
  (void)in_sizes; (void)n_in; (void)out_size; (void)ws_size;

  const float* ts = (const float*)d_in[0];
  const float* yi = (const float*)d_in[1];
  const float* w1 = (const float*)d_in[2];
  const float* b1 = (const float*)d_in[3];
  const float* w2 = (const float*)d_in[4];
  const float* b2 = (const float*)d_in[5];
  const float* w3 = (const float*)d_in[6];
  const float* b3 = (const float*)d_in[7];
  const float* Am = (const float*)d_in[8];
  float* outp = (float*)d_out;
  unsigned short* wsb = (unsigned short*)d_ws;

  (void)hipFuncSetAttribute(reinterpret_cast<const void*>(ode_kernel),
                            hipFuncAttributeMaxDynamicSharedMemorySize,
                            SMEMB);

  prep_kernel<<<400, 256, 0, stream>>>(w1, w2, w3, Am, wsb);
  ode_kernel<<<dim3(NWG), dim3(NTHR), SMEMB, stream>>>(
      ts, yi, b1, b2, b3, outp, wsb);
}